// Round 24
// baseline (118.522 us; speedup 1.0000x reference)
//
#include <hip/hip_runtime.h>

#define T_ 2048
#define E_ 1024
#define H_ 16
#define D_ 64
#define M_ 4096   // B*T

typedef unsigned short ushort_t;
typedef __attribute__((ext_vector_type(8))) short bf16x8;
typedef __attribute__((ext_vector_type(4))) float f32x4;
typedef __attribute__((ext_vector_type(8))) unsigned short u16x8;
typedef __attribute__((ext_vector_type(2))) unsigned int u32x2;

__device__ __forceinline__ ushort_t f2bf(float f) {
  union { float f; unsigned u; } v; v.f = f;
  unsigned r = v.u + 0x7FFFu + ((v.u >> 16) & 1u);
  return (ushort_t)(r >> 16);
}

__device__ __forceinline__ void gl16(const void* g, void* l) {
  __builtin_amdgcn_global_load_lds((const __attribute__((address_space(1))) void*)g,
                                   (__attribute__((address_space(3))) void*)l, 16, 0, 0);
}

// ---------------- all f32->bf16 conversions in ONE launch ----------------
__global__ __launch_bounds__(256)
void conv_all(const float* __restrict__ x,  const float* __restrict__ wq,
              const float* __restrict__ wk, const float* __restrict__ wv,
              const float* __restrict__ wp,
              ushort_t* __restrict__ xb,  ushort_t* __restrict__ wqb,
              ushort_t* __restrict__ wkb, ushort_t* __restrict__ wvb,
              ushort_t* __restrict__ wpb)
{
  const int id = blockIdx.x;
  const float* s; ushort_t* d; size_t off;
  if (id < 2048) { s = x; d = xb; off = (size_t)id * 2048; }
  else {
    int wsel = (id - 2048) >> 9, wid = (id - 2048) & 511;
    off = (size_t)wid * 2048;
    s = wsel == 0 ? wq : wsel == 1 ? wk : wsel == 2 ? wv : wp;
    d = wsel == 0 ? wqb : wsel == 1 ? wkb : wsel == 2 ? wvb : wpb;
  }
  size_t i = off + (size_t)threadIdx.x * 8;
  float4 a = *(const float4*)(s + i);
  float4 b = *(const float4*)(s + i + 4);
  u16x8 o;
  o[0]=f2bf(a.x); o[1]=f2bf(a.y); o[2]=f2bf(a.z); o[3]=f2bf(a.w);
  o[4]=f2bf(b.x); o[5]=f2bf(b.y); o[6]=f2bf(b.z); o[7]=f2bf(b.w);
  *(u16x8*)(d + i) = o;
}

// ------- 128x128x(K=1024) bf16 GEMM core, BK=32, 3-buffer counted-vmcnt (R23-passing) -------
__device__ __forceinline__ void gemm_core(const ushort_t* __restrict__ A,
                                          const ushort_t* __restrict__ W,
                                          int m0, int n0,
                                          ushort_t* As, ushort_t* Bs,
                                          f32x4 acc[4][4])
{
  const int t = threadIdx.x;
  const int lane = t & 63, w = t >> 6;
  const int g = lane >> 4, lq = lane & 15;
  const int wr = w >> 1, wc = w & 1;
  const int r0 = t >> 2;
  const int c0 = t & 3;
  const int ca0 = c0 ^ ((r0 >> 1) & 3);
  const int r1 = r0 + 64;
  const int ca1 = c0 ^ ((r1 >> 1) & 3);

  #pragma unroll
  for (int i = 0; i < 4; ++i)
    #pragma unroll
    for (int j = 0; j < 4; ++j) acc[i][j] = (f32x4){0.f,0.f,0.f,0.f};

#define STG(S_, B_)                                                             \
  do {                                                                          \
    gl16(A + (size_t)(m0 + r0) * 1024 + (S_) * 32 + ca0 * 8, As + (B_) * 4096 + t * 8);        \
    gl16(A + (size_t)(m0 + r1) * 1024 + (S_) * 32 + ca1 * 8, As + (B_) * 4096 + 2048 + t * 8); \
    gl16(W + (size_t)(n0 + r0) * 1024 + (S_) * 32 + ca0 * 8, Bs + (B_) * 4096 + t * 8);        \
    gl16(W + (size_t)(n0 + r1) * 1024 + (S_) * 32 + ca1 * 8, Bs + (B_) * 4096 + 2048 + t * 8); \
  } while (0)

  STG(0, 0);
  STG(1, 1);
  asm volatile("s_waitcnt vmcnt(4)" ::: "memory");
  __builtin_amdgcn_s_barrier();

  for (int k = 0; k < 32; ++k) {
    const int cb = k % 3;
    if (k + 2 < 32) STG(k + 2, (k + 2) % 3);

    const ushort_t* as = As + cb * 4096;
    const ushort_t* bs = Bs + cb * 4096;

    bf16x8 af[4], bfr[4];
    #pragma unroll
    for (int mi = 0; mi < 4; ++mi) {
      int row = wr * 64 + mi * 16 + lq;
      int ch = g ^ ((row >> 1) & 3);
      af[mi] = *(const bf16x8*)(as + row * 32 + ch * 8);
    }
    #pragma unroll
    for (int ni = 0; ni < 4; ++ni) {
      int row = wc * 64 + ni * 16 + lq;
      int ch = g ^ ((row >> 1) & 3);
      bfr[ni] = *(const bf16x8*)(bs + row * 32 + ch * 8);
    }
    __builtin_amdgcn_s_setprio(1);
    #pragma unroll
    for (int mi = 0; mi < 4; ++mi)
      #pragma unroll
      for (int ni = 0; ni < 4; ++ni)
        acc[mi][ni] = __builtin_amdgcn_mfma_f32_16x16x32_bf16(af[mi], bfr[ni], acc[mi][ni], 0, 0, 0);
    __builtin_amdgcn_s_setprio(0);

    if (k + 1 < 32) {
      if (k + 2 < 32) asm volatile("s_waitcnt vmcnt(4)" ::: "memory");
      else            asm volatile("s_waitcnt vmcnt(0)" ::: "memory");
      __builtin_amdgcn_s_barrier();
    }
  }
#undef STG
}

// Fused QKV projection. grid.x 0..23: sel = x>>3 (Q,K,V), n0 = (x&7)*128.
__global__ __launch_bounds__(256)
void gemm_qkv(const ushort_t* __restrict__ xb,
              const ushort_t* __restrict__ wqb, const ushort_t* __restrict__ wkb,
              const ushort_t* __restrict__ wvb,
              ushort_t* __restrict__ Qd, ushort_t* __restrict__ Kd, ushort_t* __restrict__ Vd)
{
  __shared__ __align__(16) ushort_t As[3 * 4096];
  __shared__ __align__(16) ushort_t Bs[3 * 4096];
  const int bx = blockIdx.x;
  const int sel = bx >> 3;
  const int n0 = (bx & 7) * 128;
  const int m0 = blockIdx.y * 128;
  const ushort_t* W = sel == 0 ? wqb : (sel == 1 ? wkb : wvb);
  f32x4 acc[4][4];
  gemm_core(xb, W, m0, n0, As, Bs, acc);

  const int t = threadIdx.x, lane = t & 63, w = t >> 6;
  const int g = lane >> 4, lq = lane & 15, wr = w >> 1, wc = w & 1;
  const float scl = (sel == 0) ? 0.125f : 1.0f;
  ushort_t* dst = sel == 0 ? Qd : (sel == 1 ? Kd : Vd);
  #pragma unroll
  for (int mi = 0; mi < 4; ++mi)
    #pragma unroll
    for (int ni = 0; ni < 4; ++ni)
      #pragma unroll
      for (int r = 0; r < 4; ++r) {
        int m = m0 + wr * 64 + mi * 16 + 4 * g + r;
        int n = n0 + wc * 64 + ni * 16 + lq;
        int b = m >> 11, tt = m & (T_ - 1);
        int h = n >> 6, d = n & (D_ - 1);
        ushort_t v = f2bf(acc[mi][ni][r] * scl);
        if (sel < 2) dst[((size_t)(b * H_ + h) * T_ + tt) * D_ + d] = v;
        else         dst[((size_t)(b * H_ + h) * D_ + d) * T_ + tt] = v;
      }
}

// Output projection, 64x128 tiles, 3-buffer counted-vmcnt: out = Ab @ Wp^T + bp. grid (8, 64).
__global__ __launch_bounds__(256)
void gemm_out64(const ushort_t* __restrict__ Ab, const ushort_t* __restrict__ wpb,
                const float* __restrict__ bias, float* __restrict__ out)
{
  __shared__ __align__(16) ushort_t As[3 * 2048];
  __shared__ __align__(16) ushort_t Bs[3 * 4096];
  const int t = threadIdx.x, lane = t & 63, w = t >> 6;
  const int g = lane >> 4, lq = lane & 15;
  const int n0 = blockIdx.x * 128;
  const int m0 = blockIdx.y * 64;
  const int r0 = t >> 2, c0 = t & 3;
  const int ca0 = c0 ^ ((r0 >> 1) & 3);
  const int r1 = r0 + 64;
  const int ca1 = c0 ^ ((r1 >> 1) & 3);

  f32x4 acc[4][2];
  #pragma unroll
  for (int i = 0; i < 4; ++i) { acc[i][0] = (f32x4){0.f,0.f,0.f,0.f}; acc[i][1] = (f32x4){0.f,0.f,0.f,0.f}; }

#define STG3(S_, B_)                                                                       \
  do {                                                                                     \
    gl16(Ab  + (size_t)(m0 + r0) * 1024 + (S_) * 32 + ca0 * 8, As + (B_) * 2048 + t * 8);  \
    gl16(wpb + (size_t)(n0 + r0) * 1024 + (S_) * 32 + ca0 * 8, Bs + (B_) * 4096 + t * 8);  \
    gl16(wpb + (size_t)(n0 + r1) * 1024 + (S_) * 32 + ca1 * 8, Bs + (B_) * 4096 + 2048 + t * 8); \
  } while (0)

  STG3(0, 0);
  STG3(1, 1);
  asm volatile("s_waitcnt vmcnt(3)" ::: "memory");
  __builtin_amdgcn_s_barrier();

  for (int k = 0; k < 32; ++k) {
    const int cb = k % 3;
    if (k + 2 < 32) STG3(k + 2, (k + 2) % 3);

    const ushort_t* as = As + cb * 2048;
    const ushort_t* bs = Bs + cb * 4096;

    bf16x8 af[4], bfr[2];
    #pragma unroll
    for (int mi = 0; mi < 4; ++mi) {
      int row = mi * 16 + lq;
      int ch = g ^ ((row >> 1) & 3);
      af[mi] = *(const bf16x8*)(as + row * 32 + ch * 8);
    }
    #pragma unroll
    for (int ni = 0; ni < 2; ++ni) {
      int row = w * 32 + ni * 16 + lq;
      int ch = g ^ ((row >> 1) & 3);
      bfr[ni] = *(const bf16x8*)(bs + row * 32 + ch * 8);
    }
    __builtin_amdgcn_s_setprio(1);
    #pragma unroll
    for (int mi = 0; mi < 4; ++mi)
      #pragma unroll
      for (int ni = 0; ni < 2; ++ni)
        acc[mi][ni] = __builtin_amdgcn_mfma_f32_16x16x32_bf16(af[mi], bfr[ni], acc[mi][ni], 0, 0, 0);
    __builtin_amdgcn_s_setprio(0);

    if (k + 1 < 32) {
      if (k + 2 < 32) asm volatile("s_waitcnt vmcnt(3)" ::: "memory");
      else            asm volatile("s_waitcnt vmcnt(0)" ::: "memory");
      __builtin_amdgcn_s_barrier();
    }
  }
#undef STG3

  #pragma unroll
  for (int mi = 0; mi < 4; ++mi)
    #pragma unroll
    for (int ni = 0; ni < 2; ++ni)
      #pragma unroll
      for (int r = 0; r < 4; ++r) {
        int m = m0 + mi * 16 + 4 * g + r;
        int n = n0 + w * 32 + ni * 16 + lq;
        out[(size_t)m * E_ + n] = acc[mi][ni][r] + bias[n];
      }
}

// -------- MFMA flash attention v15: in-block k-split + 3-buffer counted-vmcnt --------
// v14b (R21/R23-passing) with the R23-validated T4 pattern per group: consume
// buf[s%3] (staged 2 steps ago), prefetch s+2, vmcnt(4) leaves newest 4 in flight.
// Explicit post-loop barrier before the in-block combine (closes latent WAR race).
__global__ __launch_bounds__(512)
void attn_mfma(const ushort_t* __restrict__ Q, const ushort_t* __restrict__ K,
               const ushort_t* __restrict__ Vt, ushort_t* __restrict__ O)
{
  __shared__ __align__(16) ushort_t Ks[2][3][4096];   // [grp][buf]
  __shared__ __align__(16) ushort_t Vs[2][3][4096];
  __shared__ __align__(16) ushort_t Ps[2][128 * 72];
  const int t = threadIdx.x;
  const int w = t >> 6;                 // 0..7
  const int grp = w >> 2;               // 0 or 1
  const int wl = w & 3;                 // wave-in-group
  const int tl = t & 255;               // thread-in-group
  const int lane = t & 63;
  const int g = lane >> 4, lq = lane & 15;
  const int i = blockIdx.x;             // 0..511
  int qt;
  if (i < 256) qt = 15 - (i >> 5);      // gen1: heavy first
  else         qt = 7 - ((i - 256) >> 5); // gen2: anti-paired
  const int bh = i & 31;
  const int q0 = qt * 128;
  const size_t qkbase = (size_t)bh * T_ * D_;
  const size_t vbase  = (size_t)bh * D_ * T_;

  const int srow = tl >> 3, sc = tl & 7;
  const int cs0 = sc ^ (srow & 7);
  const int srow1 = srow + 32, cs1 = sc ^ (srow1 & 7);

  const int nsteps = qt + 1;
  const int ks = grp * nsteps;

  const int rowA = 32 * wl + lq, rowB = rowA + 16;
  const int qgA = q0 + rowA, qgB = q0 + rowB;
  const bf16x8 qA0 = *(const bf16x8*)(Q + qkbase + (size_t)qgA * D_ + g * 8);
  const bf16x8 qA1 = *(const bf16x8*)(Q + qkbase + (size_t)qgA * D_ + 32 + g * 8);
  const bf16x8 qB0 = *(const bf16x8*)(Q + qkbase + (size_t)qgB * D_ + g * 8);
  const bf16x8 qB1 = *(const bf16x8*)(Q + qkbase + (size_t)qgB * D_ + 32 + g * 8);

  f32x4 accA[4], accB[4];
  #pragma unroll
  for (int db = 0; db < 4; ++db) { accA[db] = (f32x4){0.f,0.f,0.f,0.f}; accB[db] = (f32x4){0.f,0.f,0.f,0.f}; }
  float mA = -1e30f, lA = 0.f, mB = -1e30f, lB = 0.f;

  ushort_t* Psg = &Ps[grp][0];

#define STAGEKV(KT_, B_)                                                              \
  do {                                                                               \
    const int _k0 = (KT_) * 64;                                                      \
    gl16(K + qkbase + (size_t)(_k0 + srow)  * D_ + cs0 * 8, &Ks[grp][B_][tl * 8]);   \
    gl16(K + qkbase + (size_t)(_k0 + srow1) * D_ + cs1 * 8, &Ks[grp][B_][2048 + tl * 8]); \
    gl16(Vt + vbase + (size_t)srow  * T_ + _k0 + cs0 * 8, &Vs[grp][B_][tl * 8]);     \
    gl16(Vt + vbase + (size_t)srow1 * T_ + _k0 + cs1 * 8, &Vs[grp][B_][2048 + tl * 8]);   \
  } while (0)

  // prologue: stage tiles ks (buf0) and ks+1 (buf1); counted wait keeps newest in flight
  STAGEKV(ks, 0);
  if (nsteps > 1) {
    STAGEKV(ks + 1, 1);
    asm volatile("s_waitcnt vmcnt(4)" ::: "memory");
  } else {
    asm volatile("s_waitcnt vmcnt(0)" ::: "memory");
  }
  __builtin_amdgcn_s_barrier();

  for (int s = 0; s < nsteps; ++s) {
    const int kt = ks + s;
    const int k0 = kt * 64;
    if (s + 2 < nsteps) STAGEKV(kt + 2, (s + 2) % 3);   // lookahead-2 prefetch
    const ushort_t* kb_ = &Ks[grp][s % 3][0];
    const ushort_t* vb_ = &Vs[grp][s % 3][0];

    f32x4 stA[4], stB[4];
    __builtin_amdgcn_s_setprio(1);
    #pragma unroll
    for (int kb = 0; kb < 4; ++kb) {
      int krow = kb * 16 + lq;
      bf16x8 ka0 = *(const bf16x8*)(kb_ + krow * 64 + ((g ^ (krow & 7)) * 8));
      bf16x8 ka1 = *(const bf16x8*)(kb_ + krow * 64 + (((4 + g) ^ (krow & 7)) * 8));
      f32x4 zA = (f32x4){0.f,0.f,0.f,0.f};
      zA = __builtin_amdgcn_mfma_f32_16x16x32_bf16(ka0, qA0, zA, 0, 0, 0);
      zA = __builtin_amdgcn_mfma_f32_16x16x32_bf16(ka1, qA1, zA, 0, 0, 0);
      stA[kb] = zA;
      f32x4 zB = (f32x4){0.f,0.f,0.f,0.f};
      zB = __builtin_amdgcn_mfma_f32_16x16x32_bf16(ka0, qB0, zB, 0, 0, 0);
      zB = __builtin_amdgcn_mfma_f32_16x16x32_bf16(ka1, qB1, zB, 0, 0, 0);
      stB[kb] = zB;
    }
    __builtin_amdgcn_s_setprio(0);

    if (kt >= 2 * qt) {
      #pragma unroll
      for (int kb = 0; kb < 4; ++kb)
        #pragma unroll
        for (int r = 0; r < 4; ++r) {
          int kg = k0 + kb * 16 + 4 * g + r;
          if (kg > qgA) stA[kb][r] = -1e30f;
          if (kg > qgB) stB[kb][r] = -1e30f;
        }
    }

    float tmA = -1e30f, tmB = -1e30f;
    #pragma unroll
    for (int kb = 0; kb < 4; ++kb)
      #pragma unroll
      for (int r = 0; r < 4; ++r) { tmA = fmaxf(tmA, stA[kb][r]); tmB = fmaxf(tmB, stB[kb][r]); }
    tmA = fmaxf(tmA, __shfl_xor(tmA, 16)); tmA = fmaxf(tmA, __shfl_xor(tmA, 32));
    tmB = fmaxf(tmB, __shfl_xor(tmB, 16)); tmB = fmaxf(tmB, __shfl_xor(tmB, 32));

    if (!__all((tmA <= mA + 8.f) && (tmB <= mB + 8.f))) {
      float mnA = fmaxf(mA, tmA), mnB = fmaxf(mB, tmB);
      float alA = __expf(mA - mnA), alB = __expf(mB - mnB);
      mA = mnA; mB = mnB;
      lA *= alA; lB *= alB;
      float alAr[4], alBr[4];
      #pragma unroll
      for (int r = 0; r < 4; ++r) { alAr[r] = __shfl(alA, 4 * g + r); alBr[r] = __shfl(alB, 4 * g + r); }
      #pragma unroll
      for (int db = 0; db < 4; ++db)
        #pragma unroll
        for (int r = 0; r < 4; ++r) { accA[db][r] *= alAr[r]; accB[db][r] *= alBr[r]; }
    }

    float tsA = 0.f, tsB = 0.f;
    #pragma unroll
    for (int kb = 0; kb < 4; ++kb) {
      float pA0 = __expf(stA[kb][0] - mA), pA1 = __expf(stA[kb][1] - mA);
      float pA2 = __expf(stA[kb][2] - mA), pA3 = __expf(stA[kb][3] - mA);
      float pB0 = __expf(stB[kb][0] - mB), pB1 = __expf(stB[kb][1] - mB);
      float pB2 = __expf(stB[kb][2] - mB), pB3 = __expf(stB[kb][3] - mB);
      tsA += (pA0 + pA1) + (pA2 + pA3);
      tsB += (pB0 + pB1) + (pB2 + pB3);
      unsigned aLo, aHi, bLo, bHi;
      asm("v_cvt_pk_bf16_f32 %0, %1, %2" : "=v"(aLo) : "v"(pA0), "v"(pA1));
      asm("v_cvt_pk_bf16_f32 %0, %1, %2" : "=v"(aHi) : "v"(pA2), "v"(pA3));
      asm("v_cvt_pk_bf16_f32 %0, %1, %2" : "=v"(bLo) : "v"(pB0), "v"(pB1));
      asm("v_cvt_pk_bf16_f32 %0, %1, %2" : "=v"(bHi) : "v"(pB2), "v"(pB3));
      *(u32x2*)(Psg + rowA * 72 + kb * 16 + 4 * g) = (u32x2){aLo, aHi};
      *(u32x2*)(Psg + rowB * 72 + kb * 16 + 4 * g) = (u32x2){bLo, bHi};
    }
    tsA += __shfl_xor(tsA, 16); tsA += __shfl_xor(tsA, 32);
    tsB += __shfl_xor(tsB, 16); tsB += __shfl_xor(tsB, 32);
    lA += tsA; lB += tsB;

    asm volatile("s_waitcnt lgkmcnt(0)" ::: "memory");
    bf16x8 paA0 = *(const bf16x8*)(Psg + rowA * 72 + g * 8);
    bf16x8 paA1 = *(const bf16x8*)(Psg + rowA * 72 + 32 + g * 8);
    bf16x8 paB0 = *(const bf16x8*)(Psg + rowB * 72 + g * 8);
    bf16x8 paB1 = *(const bf16x8*)(Psg + rowB * 72 + 32 + g * 8);

    __builtin_amdgcn_s_setprio(1);
    #pragma unroll
    for (int db = 0; db < 4; ++db) {
      int vrow = db * 16 + lq;
      bf16x8 vb0 = *(const bf16x8*)(vb_ + vrow * 64 + ((g ^ (vrow & 7)) * 8));
      bf16x8 vb1 = *(const bf16x8*)(vb_ + vrow * 64 + (((4 + g) ^ (vrow & 7)) * 8));
      accA[db] = __builtin_amdgcn_mfma_f32_16x16x32_bf16(paA0, vb0, accA[db], 0, 0, 0);
      accA[db] = __builtin_amdgcn_mfma_f32_16x16x32_bf16(paA1, vb1, accA[db], 0, 0, 0);
      accB[db] = __builtin_amdgcn_mfma_f32_16x16x32_bf16(paB0, vb0, accB[db], 0, 0, 0);
      accB[db] = __builtin_amdgcn_mfma_f32_16x16x32_bf16(paB1, vb1, accB[db], 0, 0, 0);
    }
    __builtin_amdgcn_s_setprio(0);

    if (s + 1 < nsteps) {
      if (s + 2 < nsteps) asm volatile("s_waitcnt vmcnt(4)" ::: "memory");
      else                asm volatile("s_waitcnt vmcnt(0)" ::: "memory");
      __builtin_amdgcn_s_barrier();
    }
  }
#undef STAGEKV

  // all tile reads complete in both groups before scratch aliasing (closes WAR race)
  __builtin_amdgcn_s_barrier();

  // ---- in-block flash-combine (scratch aliases Ks/Vs) ----
  float* accS = (float*)&Ks[0][0][0];   // 256 thr * 32 f32 = 32KB
  float* mlS  = (float*)&Vs[0][0][0];   // 256 thr * 4  f32 = 4KB
  if (grp == 1) {
    #pragma unroll
    for (int db = 0; db < 4; ++db)
      #pragma unroll
      for (int r = 0; r < 4; ++r) {
        accS[tl * 32 + db * 4 + r]      = accA[db][r];
        accS[tl * 32 + 16 + db * 4 + r] = accB[db][r];
      }
    mlS[tl * 4 + 0] = mA; mlS[tl * 4 + 1] = lA;
    mlS[tl * 4 + 2] = mB; mlS[tl * 4 + 3] = lB;
  }
  asm volatile("s_waitcnt lgkmcnt(0)" ::: "memory");
  __builtin_amdgcn_s_barrier();
  if (grp == 0) {
    const float m1A = mlS[tl * 4 + 0], l1A = mlS[tl * 4 + 1];
    const float m1B = mlS[tl * 4 + 2], l1B = mlS[tl * 4 + 3];
    const float moA = fmaxf(mA, m1A);
    const float c0 = __expf(mA - moA), c1 = __expf(m1A - moA);
    lA = lA * c0 + l1A * c1;
    const float moB = fmaxf(mB, m1B);
    const float d0 = __expf(mB - moB), d1 = __expf(m1B - moB);
    lB = lB * d0 + l1B * d1;
    float c0r[4], c1r[4], d0r[4], d1r[4];
    #pragma unroll
    for (int r = 0; r < 4; ++r) {
      c0r[r] = __shfl(c0, 4 * g + r); c1r[r] = __shfl(c1, 4 * g + r);
      d0r[r] = __shfl(d0, 4 * g + r); d1r[r] = __shfl(d1, 4 * g + r);
    }
    #pragma unroll
    for (int db = 0; db < 4; ++db)
      #pragma unroll
      for (int r = 0; r < 4; ++r) {
        accA[db][r] = accA[db][r] * c0r[r] + accS[tl * 32 + db * 4 + r] * c1r[r];
        accB[db][r] = accB[db][r] * d0r[r] + accS[tl * 32 + 16 + db * 4 + r] * d1r[r];
      }

    float invA = 1.0f / lA, invB = 1.0f / lB;
    float liA[4], liB[4];
    #pragma unroll
    for (int r = 0; r < 4; ++r) { liA[r] = __shfl(invA, 4 * g + r); liB[r] = __shfl(invB, 4 * g + r); }
    const int b = bh >> 4, h = bh & 15;
    #pragma unroll
    for (int db = 0; db < 4; ++db)
      #pragma unroll
      for (int r = 0; r < 4; ++r) {
        int mAo = q0 + 32 * wl + 4 * g + r;
        int mBo = mAo + 16;
        O[((size_t)(b * T_ + mAo)) * E_ + h * 64 + db * 16 + lq] = f2bf(accA[db][r] * liA[r]);
        O[((size_t)(b * T_ + mBo)) * E_ + h * 64 + db * 16 + lq] = f2bf(accB[db][r] * liB[r]);
      }
  }
}

extern "C" void kernel_launch(void* const* d_in, const int* in_sizes, int n_in,
                              void* d_out, int out_size, void* d_ws, size_t ws_size,
                              hipStream_t stream) {
  const float* x  = (const float*)d_in[0];
  const float* Wq = (const float*)d_in[1];
  const float* Wk = (const float*)d_in[2];
  const float* Wv = (const float*)d_in[3];
  const float* Wp = (const float*)d_in[4];
  const float* bp = (const float*)d_in[5];
  float* out = (float*)d_out;

  ushort_t* ws  = (ushort_t*)d_ws;
  ushort_t* xb  = ws;
  ushort_t* wqb = xb  + (size_t)M_ * E_;
  ushort_t* wkb = wqb + (size_t)E_ * E_;
  ushort_t* wvb = wkb + (size_t)E_ * E_;
  ushort_t* wpb = wvb + (size_t)E_ * E_;
  ushort_t* Qb  = wpb + (size_t)E_ * E_;
  ushort_t* Kb  = Qb  + (size_t)M_ * E_;
  ushort_t* Vb  = Kb  + (size_t)M_ * E_;
  ushort_t* Ab  = Vb  + (size_t)M_ * E_;

  conv_all<<<4096, 256, 0, stream>>>(x, Wq, Wk, Wv, Wp, xb, wqb, wkb, wvb, wpb);
  gemm_qkv<<<dim3(24, 32), 256, 0, stream>>>(xb, wqb, wkb, wvb, Qb, Kb, Vb);
  attn_mfma<<<512, 512, 0, stream>>>(Qb, Kb, Vb, Ab);
  gemm_out64<<<dim3(8, 64), 256, 0, stream>>>(Ab, wpb, bp, out);
}

// Round 25
// 114.353 us; speedup vs baseline: 1.0365x; 1.0365x over previous
//
#include <hip/hip_runtime.h>

#define T_ 2048
#define E_ 1024
#define H_ 16
#define D_ 64
#define M_ 4096   // B*T

typedef unsigned short ushort_t;
typedef __attribute__((ext_vector_type(8))) short bf16x8;
typedef __attribute__((ext_vector_type(4))) float f32x4;
typedef __attribute__((ext_vector_type(8))) unsigned short u16x8;
typedef __attribute__((ext_vector_type(2))) unsigned int u32x2;

__device__ __forceinline__ ushort_t f2bf(float f) {
  union { float f; unsigned u; } v; v.f = f;
  unsigned r = v.u + 0x7FFFu + ((v.u >> 16) & 1u);
  return (ushort_t)(r >> 16);
}

__device__ __forceinline__ void gl16(const void* g, void* l) {
  __builtin_amdgcn_global_load_lds((const __attribute__((address_space(1))) void*)g,
                                   (__attribute__((address_space(3))) void*)l, 16, 0, 0);
}

// ---------------- all f32->bf16 conversions in ONE launch ----------------
__global__ __launch_bounds__(256)
void conv_all(const float* __restrict__ x,  const float* __restrict__ wq,
              const float* __restrict__ wk, const float* __restrict__ wv,
              const float* __restrict__ wp,
              ushort_t* __restrict__ xb,  ushort_t* __restrict__ wqb,
              ushort_t* __restrict__ wkb, ushort_t* __restrict__ wvb,
              ushort_t* __restrict__ wpb)
{
  const int id = blockIdx.x;
  const float* s; ushort_t* d; size_t off;
  if (id < 2048) { s = x; d = xb; off = (size_t)id * 2048; }
  else {
    int wsel = (id - 2048) >> 9, wid = (id - 2048) & 511;
    off = (size_t)wid * 2048;
    s = wsel == 0 ? wq : wsel == 1 ? wk : wsel == 2 ? wv : wp;
    d = wsel == 0 ? wqb : wsel == 1 ? wkb : wsel == 2 ? wvb : wpb;
  }
  size_t i = off + (size_t)threadIdx.x * 8;
  float4 a = *(const float4*)(s + i);
  float4 b = *(const float4*)(s + i + 4);
  u16x8 o;
  o[0]=f2bf(a.x); o[1]=f2bf(a.y); o[2]=f2bf(a.z); o[3]=f2bf(a.w);
  o[4]=f2bf(b.x); o[5]=f2bf(b.y); o[6]=f2bf(b.z); o[7]=f2bf(b.w);
  *(u16x8*)(d + i) = o;
}

// ------- 128x128x(K=1024) bf16 GEMM core, Y = A @ W^T, 2-phase pipelined -------
__device__ __forceinline__ void gemm_core(const ushort_t* __restrict__ A,
                                          const ushort_t* __restrict__ W,
                                          int m0, int n0,
                                          ushort_t* As, ushort_t* Bs,
                                          f32x4 acc[4][4])
{
  const int t = threadIdx.x;
  const int lane = t & 63, w = t >> 6;
  const int g = lane >> 4, lq = lane & 15;
  const int wr = w >> 1, wc = w & 1;
  const int r0 = t >> 2;
  const int c0 = t & 3;
  const int ca0 = c0 ^ ((r0 >> 1) & 3);
  const int r1 = r0 + 64;
  const int ca1 = c0 ^ ((r1 >> 1) & 3);

  #pragma unroll
  for (int i = 0; i < 4; ++i)
    #pragma unroll
    for (int j = 0; j < 4; ++j) acc[i][j] = (f32x4){0.f,0.f,0.f,0.f};

  gl16(A + (size_t)(m0 + r0) * 1024 + ca0 * 8, As + t * 8);
  gl16(A + (size_t)(m0 + r1) * 1024 + ca1 * 8, As + 2048 + t * 8);
  gl16(W + (size_t)(n0 + r0) * 1024 + ca0 * 8, Bs + t * 8);
  gl16(W + (size_t)(n0 + r1) * 1024 + ca1 * 8, Bs + 2048 + t * 8);
  __syncthreads();

  int cur = 0;
  for (int k0 = 0; k0 < 1024; k0 += 32) {
    if (k0 + 32 < 1024) {
      const int nx = (cur ^ 1) * 4096;
      gl16(A + (size_t)(m0 + r0) * 1024 + k0 + 32 + ca0 * 8, As + nx + t * 8);
      gl16(A + (size_t)(m0 + r1) * 1024 + k0 + 32 + ca1 * 8, As + nx + 2048 + t * 8);
      gl16(W + (size_t)(n0 + r0) * 1024 + k0 + 32 + ca0 * 8, Bs + nx + t * 8);
      gl16(W + (size_t)(n0 + r1) * 1024 + k0 + 32 + ca1 * 8, Bs + nx + 2048 + t * 8);
    }
    const ushort_t* as = As + cur * 4096;
    const ushort_t* bs = Bs + cur * 4096;

    bf16x8 af[4], bfr[4];
    #pragma unroll
    for (int mi = 0; mi < 4; ++mi) {
      int row = wr * 64 + mi * 16 + lq;
      int ch = g ^ ((row >> 1) & 3);
      af[mi] = *(const bf16x8*)(as + row * 32 + ch * 8);
    }
    #pragma unroll
    for (int ni = 0; ni < 4; ++ni) {
      int row = wc * 64 + ni * 16 + lq;
      int ch = g ^ ((row >> 1) & 3);
      bfr[ni] = *(const bf16x8*)(bs + row * 32 + ch * 8);
    }
    __builtin_amdgcn_s_setprio(1);
    #pragma unroll
    for (int mi = 0; mi < 4; ++mi)
      #pragma unroll
      for (int ni = 0; ni < 4; ++ni)
        acc[mi][ni] = __builtin_amdgcn_mfma_f32_16x16x32_bf16(af[mi], bfr[ni], acc[mi][ni], 0, 0, 0);
    __builtin_amdgcn_s_setprio(0);

    __syncthreads();
    cur ^= 1;
  }
}

// Fused QKV projection. grid.x 0..23: sel = x>>3 (Q,K,V), n0 = (x&7)*128.
__global__ __launch_bounds__(256)
void gemm_qkv(const ushort_t* __restrict__ xb,
              const ushort_t* __restrict__ wqb, const ushort_t* __restrict__ wkb,
              const ushort_t* __restrict__ wvb,
              ushort_t* __restrict__ Qd, ushort_t* __restrict__ Kd, ushort_t* __restrict__ Vd)
{
  __shared__ __align__(16) ushort_t As[2 * 4096];
  __shared__ __align__(16) ushort_t Bs[2 * 4096];
  const int bx = blockIdx.x;
  const int sel = bx >> 3;
  const int n0 = (bx & 7) * 128;
  const int m0 = blockIdx.y * 128;
  const ushort_t* W = sel == 0 ? wqb : (sel == 1 ? wkb : wvb);
  f32x4 acc[4][4];
  gemm_core(xb, W, m0, n0, As, Bs, acc);

  const int t = threadIdx.x, lane = t & 63, w = t >> 6;
  const int g = lane >> 4, lq = lane & 15, wr = w >> 1, wc = w & 1;
  const float scl = (sel == 0) ? 0.125f : 1.0f;
  ushort_t* dst = sel == 0 ? Qd : (sel == 1 ? Kd : Vd);
  #pragma unroll
  for (int mi = 0; mi < 4; ++mi)
    #pragma unroll
    for (int ni = 0; ni < 4; ++ni)
      #pragma unroll
      for (int r = 0; r < 4; ++r) {
        int m = m0 + wr * 64 + mi * 16 + 4 * g + r;
        int n = n0 + wc * 64 + ni * 16 + lq;
        int b = m >> 11, tt = m & (T_ - 1);
        int h = n >> 6, d = n & (D_ - 1);
        ushort_t v = f2bf(acc[mi][ni][r] * scl);
        if (sel < 2) dst[((size_t)(b * H_ + h) * T_ + tt) * D_ + d] = v;
        else         dst[((size_t)(b * H_ + h) * D_ + d) * T_ + tt] = v;
      }
}

// Output projection, 64x128 tiles, 2-phase pipelined: out = Ab @ Wp^T + bp. grid (8, 64).
__global__ __launch_bounds__(256)
void gemm_out64(const ushort_t* __restrict__ Ab, const ushort_t* __restrict__ wpb,
                const float* __restrict__ bias, float* __restrict__ out)
{
  __shared__ __align__(16) ushort_t As[2 * 2048];
  __shared__ __align__(16) ushort_t Bs[2 * 4096];
  const int t = threadIdx.x, lane = t & 63, w = t >> 6;
  const int g = lane >> 4, lq = lane & 15;
  const int n0 = blockIdx.x * 128;
  const int m0 = blockIdx.y * 64;
  const int r0 = t >> 2, c0 = t & 3;
  const int ca0 = c0 ^ ((r0 >> 1) & 3);
  const int r1 = r0 + 64;
  const int ca1 = c0 ^ ((r1 >> 1) & 3);

  f32x4 acc[4][2];
  #pragma unroll
  for (int i = 0; i < 4; ++i) { acc[i][0] = (f32x4){0.f,0.f,0.f,0.f}; acc[i][1] = (f32x4){0.f,0.f,0.f,0.f}; }

  gl16(Ab  + (size_t)(m0 + r0) * 1024 + ca0 * 8, As + t * 8);
  gl16(wpb + (size_t)(n0 + r0) * 1024 + ca0 * 8, Bs + t * 8);
  gl16(wpb + (size_t)(n0 + r1) * 1024 + ca1 * 8, Bs + 2048 + t * 8);
  __syncthreads();

  int cur = 0;
  for (int k0 = 0; k0 < 1024; k0 += 32) {
    if (k0 + 32 < 1024) {
      gl16(Ab  + (size_t)(m0 + r0) * 1024 + k0 + 32 + ca0 * 8, As + (cur ^ 1) * 2048 + t * 8);
      gl16(wpb + (size_t)(n0 + r0) * 1024 + k0 + 32 + ca0 * 8, Bs + (cur ^ 1) * 4096 + t * 8);
      gl16(wpb + (size_t)(n0 + r1) * 1024 + k0 + 32 + ca1 * 8, Bs + (cur ^ 1) * 4096 + 2048 + t * 8);
    }
    const ushort_t* as = As + cur * 2048;
    const ushort_t* bs = Bs + cur * 4096;

    bf16x8 af[4], bfr[2];
    #pragma unroll
    for (int mi = 0; mi < 4; ++mi) {
      int row = mi * 16 + lq;
      int ch = g ^ ((row >> 1) & 3);
      af[mi] = *(const bf16x8*)(as + row * 32 + ch * 8);
    }
    #pragma unroll
    for (int ni = 0; ni < 2; ++ni) {
      int row = w * 32 + ni * 16 + lq;
      int ch = g ^ ((row >> 1) & 3);
      bfr[ni] = *(const bf16x8*)(bs + row * 32 + ch * 8);
    }
    __builtin_amdgcn_s_setprio(1);
    #pragma unroll
    for (int mi = 0; mi < 4; ++mi)
      #pragma unroll
      for (int ni = 0; ni < 2; ++ni)
        acc[mi][ni] = __builtin_amdgcn_mfma_f32_16x16x32_bf16(af[mi], bfr[ni], acc[mi][ni], 0, 0, 0);
    __builtin_amdgcn_s_setprio(0);

    __syncthreads();
    cur ^= 1;
  }
  #pragma unroll
  for (int mi = 0; mi < 4; ++mi)
    #pragma unroll
    for (int ni = 0; ni < 2; ++ni)
      #pragma unroll
      for (int r = 0; r < 4; ++r) {
        int m = m0 + mi * 16 + 4 * g + r;
        int n = n0 + w * 32 + ni * 16 + lq;
        out[(size_t)m * E_ + n] = acc[mi][ni][r] + bias[n];
      }
}

// -------- MFMA flash attention v14b: IN-BLOCK k-split (R21-measured-best, verbatim) --------
__global__ __launch_bounds__(512)
void attn_mfma(const ushort_t* __restrict__ Q, const ushort_t* __restrict__ K,
               const ushort_t* __restrict__ Vt, ushort_t* __restrict__ O)
{
  __shared__ __align__(16) ushort_t Ks[2][2][4096];   // [grp][buf]
  __shared__ __align__(16) ushort_t Vs[2][2][4096];
  __shared__ __align__(16) ushort_t Ps[2][128 * 72];
  const int t = threadIdx.x;
  const int w = t >> 6;                 // 0..7
  const int grp = w >> 2;               // 0 or 1
  const int wl = w & 3;                 // wave-in-group
  const int tl = t & 255;               // thread-in-group
  const int lane = t & 63;
  const int g = lane >> 4, lq = lane & 15;
  const int i = blockIdx.x;             // 0..511
  int qt;
  if (i < 256) qt = 15 - (i >> 5);      // gen1: heavy first
  else         qt = 7 - ((i - 256) >> 5); // gen2: anti-paired
  const int bh = i & 31;
  const int q0 = qt * 128;
  const size_t qkbase = (size_t)bh * T_ * D_;
  const size_t vbase  = (size_t)bh * D_ * T_;

  const int srow = tl >> 3, sc = tl & 7;
  const int cs0 = sc ^ (srow & 7);
  const int srow1 = srow + 32, cs1 = sc ^ (srow1 & 7);

  const int nsteps = qt + 1;
  const int ks = grp * nsteps;

  const int rowA = 32 * wl + lq, rowB = rowA + 16;
  const int qgA = q0 + rowA, qgB = q0 + rowB;
  const bf16x8 qA0 = *(const bf16x8*)(Q + qkbase + (size_t)qgA * D_ + g * 8);
  const bf16x8 qA1 = *(const bf16x8*)(Q + qkbase + (size_t)qgA * D_ + 32 + g * 8);
  const bf16x8 qB0 = *(const bf16x8*)(Q + qkbase + (size_t)qgB * D_ + g * 8);
  const bf16x8 qB1 = *(const bf16x8*)(Q + qkbase + (size_t)qgB * D_ + 32 + g * 8);

  f32x4 accA[4], accB[4];
  #pragma unroll
  for (int db = 0; db < 4; ++db) { accA[db] = (f32x4){0.f,0.f,0.f,0.f}; accB[db] = (f32x4){0.f,0.f,0.f,0.f}; }
  float mA = -1e30f, lA = 0.f, mB = -1e30f, lB = 0.f;

  ushort_t* Psg = &Ps[grp][0];

  {
    const int k0p = ks * 64;
    gl16(K + qkbase + (size_t)(k0p + srow)  * D_ + cs0 * 8, &Ks[grp][0][tl * 8]);
    gl16(K + qkbase + (size_t)(k0p + srow1) * D_ + cs1 * 8, &Ks[grp][0][2048 + tl * 8]);
    gl16(Vt + vbase + (size_t)srow  * T_ + k0p + cs0 * 8, &Vs[grp][0][tl * 8]);
    gl16(Vt + vbase + (size_t)srow1 * T_ + k0p + cs1 * 8, &Vs[grp][0][2048 + tl * 8]);
  }
  asm volatile("s_waitcnt vmcnt(0)" ::: "memory");
  __builtin_amdgcn_s_barrier();

  for (int s = 0; s < nsteps; ++s) {
    const int kt = ks + s;
    const int cur = s & 1;
    const int k0 = kt * 64;
    if (s + 1 < nsteps) {
      const int kn = (kt + 1) * 64;
      gl16(K + qkbase + (size_t)(kn + srow)  * D_ + cs0 * 8, &Ks[grp][cur ^ 1][tl * 8]);
      gl16(K + qkbase + (size_t)(kn + srow1) * D_ + cs1 * 8, &Ks[grp][cur ^ 1][2048 + tl * 8]);
      gl16(Vt + vbase + (size_t)srow  * T_ + kn + cs0 * 8, &Vs[grp][cur ^ 1][tl * 8]);
      gl16(Vt + vbase + (size_t)srow1 * T_ + kn + cs1 * 8, &Vs[grp][cur ^ 1][2048 + tl * 8]);
    }
    const ushort_t* kb_ = &Ks[grp][cur][0];
    const ushort_t* vb_ = &Vs[grp][cur][0];

    f32x4 stA[4], stB[4];
    __builtin_amdgcn_s_setprio(1);
    #pragma unroll
    for (int kb = 0; kb < 4; ++kb) {
      int krow = kb * 16 + lq;
      bf16x8 ka0 = *(const bf16x8*)(kb_ + krow * 64 + ((g ^ (krow & 7)) * 8));
      bf16x8 ka1 = *(const bf16x8*)(kb_ + krow * 64 + (((4 + g) ^ (krow & 7)) * 8));
      f32x4 zA = (f32x4){0.f,0.f,0.f,0.f};
      zA = __builtin_amdgcn_mfma_f32_16x16x32_bf16(ka0, qA0, zA, 0, 0, 0);
      zA = __builtin_amdgcn_mfma_f32_16x16x32_bf16(ka1, qA1, zA, 0, 0, 0);
      stA[kb] = zA;
      f32x4 zB = (f32x4){0.f,0.f,0.f,0.f};
      zB = __builtin_amdgcn_mfma_f32_16x16x32_bf16(ka0, qB0, zB, 0, 0, 0);
      zB = __builtin_amdgcn_mfma_f32_16x16x32_bf16(ka1, qB1, zB, 0, 0, 0);
      stB[kb] = zB;
    }
    __builtin_amdgcn_s_setprio(0);

    if (kt >= 2 * qt) {
      #pragma unroll
      for (int kb = 0; kb < 4; ++kb)
        #pragma unroll
        for (int r = 0; r < 4; ++r) {
          int kg = k0 + kb * 16 + 4 * g + r;
          if (kg > qgA) stA[kb][r] = -1e30f;
          if (kg > qgB) stB[kb][r] = -1e30f;
        }
    }

    float tmA = -1e30f, tmB = -1e30f;
    #pragma unroll
    for (int kb = 0; kb < 4; ++kb)
      #pragma unroll
      for (int r = 0; r < 4; ++r) { tmA = fmaxf(tmA, stA[kb][r]); tmB = fmaxf(tmB, stB[kb][r]); }
    tmA = fmaxf(tmA, __shfl_xor(tmA, 16)); tmA = fmaxf(tmA, __shfl_xor(tmA, 32));
    tmB = fmaxf(tmB, __shfl_xor(tmB, 16)); tmB = fmaxf(tmB, __shfl_xor(tmB, 32));

    if (!__all((tmA <= mA + 8.f) && (tmB <= mB + 8.f))) {
      float mnA = fmaxf(mA, tmA), mnB = fmaxf(mB, tmB);
      float alA = __expf(mA - mnA), alB = __expf(mB - mnB);
      mA = mnA; mB = mnB;
      lA *= alA; lB *= alB;
      float alAr[4], alBr[4];
      #pragma unroll
      for (int r = 0; r < 4; ++r) { alAr[r] = __shfl(alA, 4 * g + r); alBr[r] = __shfl(alB, 4 * g + r); }
      #pragma unroll
      for (int db = 0; db < 4; ++db)
        #pragma unroll
        for (int r = 0; r < 4; ++r) { accA[db][r] *= alAr[r]; accB[db][r] *= alBr[r]; }
    }

    float tsA = 0.f, tsB = 0.f;
    #pragma unroll
    for (int kb = 0; kb < 4; ++kb) {
      float pA0 = __expf(stA[kb][0] - mA), pA1 = __expf(stA[kb][1] - mA);
      float pA2 = __expf(stA[kb][2] - mA), pA3 = __expf(stA[kb][3] - mA);
      float pB0 = __expf(stB[kb][0] - mB), pB1 = __expf(stB[kb][1] - mB);
      float pB2 = __expf(stB[kb][2] - mB), pB3 = __expf(stB[kb][3] - mB);
      tsA += (pA0 + pA1) + (pA2 + pA3);
      tsB += (pB0 + pB1) + (pB2 + pB3);
      unsigned aLo, aHi, bLo, bHi;
      asm("v_cvt_pk_bf16_f32 %0, %1, %2" : "=v"(aLo) : "v"(pA0), "v"(pA1));
      asm("v_cvt_pk_bf16_f32 %0, %1, %2" : "=v"(aHi) : "v"(pA2), "v"(pA3));
      asm("v_cvt_pk_bf16_f32 %0, %1, %2" : "=v"(bLo) : "v"(pB0), "v"(pB1));
      asm("v_cvt_pk_bf16_f32 %0, %1, %2" : "=v"(bHi) : "v"(pB2), "v"(pB3));
      *(u32x2*)(Psg + rowA * 72 + kb * 16 + 4 * g) = (u32x2){aLo, aHi};
      *(u32x2*)(Psg + rowB * 72 + kb * 16 + 4 * g) = (u32x2){bLo, bHi};
    }
    tsA += __shfl_xor(tsA, 16); tsA += __shfl_xor(tsA, 32);
    tsB += __shfl_xor(tsB, 16); tsB += __shfl_xor(tsB, 32);
    lA += tsA; lB += tsB;

    asm volatile("s_waitcnt lgkmcnt(0)" ::: "memory");
    bf16x8 paA0 = *(const bf16x8*)(Psg + rowA * 72 + g * 8);
    bf16x8 paA1 = *(const bf16x8*)(Psg + rowA * 72 + 32 + g * 8);
    bf16x8 paB0 = *(const bf16x8*)(Psg + rowB * 72 + g * 8);
    bf16x8 paB1 = *(const bf16x8*)(Psg + rowB * 72 + 32 + g * 8);

    __builtin_amdgcn_s_setprio(1);
    #pragma unroll
    for (int db = 0; db < 4; ++db) {
      int vrow = db * 16 + lq;
      bf16x8 vb0 = *(const bf16x8*)(vb_ + vrow * 64 + ((g ^ (vrow & 7)) * 8));
      bf16x8 vb1 = *(const bf16x8*)(vb_ + vrow * 64 + (((4 + g) ^ (vrow & 7)) * 8));
      accA[db] = __builtin_amdgcn_mfma_f32_16x16x32_bf16(paA0, vb0, accA[db], 0, 0, 0);
      accA[db] = __builtin_amdgcn_mfma_f32_16x16x32_bf16(paA1, vb1, accA[db], 0, 0, 0);
      accB[db] = __builtin_amdgcn_mfma_f32_16x16x32_bf16(paB0, vb0, accB[db], 0, 0, 0);
      accB[db] = __builtin_amdgcn_mfma_f32_16x16x32_bf16(paB1, vb1, accB[db], 0, 0, 0);
    }
    __builtin_amdgcn_s_setprio(0);

    if (s + 1 < nsteps) asm volatile("s_waitcnt vmcnt(0)" ::: "memory");
    __builtin_amdgcn_s_barrier();
  }

  // ---- in-block flash-combine ----
  float* accS = (float*)&Ks[0][0][0];
  float* mlS  = (float*)&Vs[0][0][0];
  if (grp == 1) {
    #pragma unroll
    for (int db = 0; db < 4; ++db)
      #pragma unroll
      for (int r = 0; r < 4; ++r) {
        accS[tl * 32 + db * 4 + r]      = accA[db][r];
        accS[tl * 32 + 16 + db * 4 + r] = accB[db][r];
      }
    mlS[tl * 4 + 0] = mA; mlS[tl * 4 + 1] = lA;
    mlS[tl * 4 + 2] = mB; mlS[tl * 4 + 3] = lB;
  }
  asm volatile("s_waitcnt lgkmcnt(0)" ::: "memory");
  __builtin_amdgcn_s_barrier();
  if (grp == 0) {
    const float m1A = mlS[tl * 4 + 0], l1A = mlS[tl * 4 + 1];
    const float m1B = mlS[tl * 4 + 2], l1B = mlS[tl * 4 + 3];
    const float moA = fmaxf(mA, m1A);
    const float c0 = __expf(mA - moA), c1 = __expf(m1A - moA);
    lA = lA * c0 + l1A * c1;
    const float moB = fmaxf(mB, m1B);
    const float d0 = __expf(mB - moB), d1 = __expf(m1B - moB);
    lB = lB * d0 + l1B * d1;
    float c0r[4], c1r[4], d0r[4], d1r[4];
    #pragma unroll
    for (int r = 0; r < 4; ++r) {
      c0r[r] = __shfl(c0, 4 * g + r); c1r[r] = __shfl(c1, 4 * g + r);
      d0r[r] = __shfl(d0, 4 * g + r); d1r[r] = __shfl(d1, 4 * g + r);
    }
    #pragma unroll
    for (int db = 0; db < 4; ++db)
      #pragma unroll
      for (int r = 0; r < 4; ++r) {
        accA[db][r] = accA[db][r] * c0r[r] + accS[tl * 32 + db * 4 + r] * c1r[r];
        accB[db][r] = accB[db][r] * d0r[r] + accS[tl * 32 + 16 + db * 4 + r] * d1r[r];
      }

    float invA = 1.0f / lA, invB = 1.0f / lB;
    float liA[4], liB[4];
    #pragma unroll
    for (int r = 0; r < 4; ++r) { liA[r] = __shfl(invA, 4 * g + r); liB[r] = __shfl(invB, 4 * g + r); }
    const int b = bh >> 4, h = bh & 15;
    #pragma unroll
    for (int db = 0; db < 4; ++db)
      #pragma unroll
      for (int r = 0; r < 4; ++r) {
        int mAo = q0 + 32 * wl + 4 * g + r;
        int mBo = mAo + 16;
        O[((size_t)(b * T_ + mAo)) * E_ + h * 64 + db * 16 + lq] = f2bf(accA[db][r] * liA[r]);
        O[((size_t)(b * T_ + mBo)) * E_ + h * 64 + db * 16 + lq] = f2bf(accB[db][r] * liB[r]);
      }
  }
}

extern "C" void kernel_launch(void* const* d_in, const int* in_sizes, int n_in,
                              void* d_out, int out_size, void* d_ws, size_t ws_size,
                              hipStream_t stream) {
  const float* x  = (const float*)d_in[0];
  const float* Wq = (const float*)d_in[1];
  const float* Wk = (const float*)d_in[2];
  const float* Wv = (const float*)d_in[3];
  const float* Wp = (const float*)d_in[4];
  const float* bp = (const float*)d_in[5];
  float* out = (float*)d_out;

  ushort_t* ws  = (ushort_t*)d_ws;
  ushort_t* xb  = ws;
  ushort_t* wqb = xb  + (size_t)M_ * E_;
  ushort_t* wkb = wqb + (size_t)E_ * E_;
  ushort_t* wvb = wkb + (size_t)E_ * E_;
  ushort_t* wpb = wvb + (size_t)E_ * E_;
  ushort_t* Qb  = wpb + (size_t)E_ * E_;
  ushort_t* Kb  = Qb  + (size_t)M_ * E_;
  ushort_t* Vb  = Kb  + (size_t)M_ * E_;
  ushort_t* Ab  = Vb  + (size_t)M_ * E_;

  conv_all<<<4096, 256, 0, stream>>>(x, Wq, Wk, Wv, Wp, xb, wqb, wkb, wvb, wpb);
  gemm_qkv<<<dim3(24, 32), 256, 0, stream>>>(xb, wqb, wkb, wvb, Qb, Kb, Vb);
  attn_mfma<<<512, 512, 0, stream>>>(Qb, Kb, Vb, Ab);
  gemm_out64<<<dim3(8, 64), 256, 0, stream>>>(Ab, wpb, bp, out);
}